// Round 2
// baseline (652.810 us; speedup 1.0000x reference)
//
#include <hip/hip_runtime.h>
#include <math.h>

namespace {
constexpr int Bn = 4;
constexpr int Cn = 256;
constexpr int Kn = 19;
constexpr int HW = 256 * 256;          // 65536
constexpr int P  = Bn * HW;            // 262144 pixels
constexpr float TAUv = 0.07f;
constexpr float EPSv = 1e-12f;

// workspace layout (floats)
constexpr int K0_OFF   = 0;            // [19][256] prototype accumulators
constexpr int K0N_OFF  = 4864;         // [19][256] normalized prototypes (row-major)
constexpr int SUMS_OFF = 9728;         // {loss_sum, num_pos}
constexpr int P1_GRID  = 512;
constexpr int ZERO_N   = 9730;
}

__global__ __launch_bounds__(256) void gc_init(float* __restrict__ ws) {
  int i = blockIdx.x * 256 + threadIdx.x;
  if (i < ZERO_N) ws[i] = 0.0f;
}

// Phase 1: k0[k][c] = sum over pixels of pos[k,p] * fnorm[c,p]
// Block: 256 threads; thread t accumulates channel c=t across 19 classes.
// Tile: 64 pixels x 256 channels staged in LDS (XOR-swizzled).
__global__ __launch_bounds__(256, 2) void gc_phase1(const float* __restrict__ feat,
                                                    const float* __restrict__ gt,
                                                    float* __restrict__ k0) {
  __shared__ float tile[64 * 256];   // 64 KB; [p][c ^ (p&31)]
  __shared__ float part[256];        // per-(wave,pixel) sumsq partials
  __shared__ float2 pm[64];          // per-pixel {rnorm, bitcast(mask)}

  const int t    = threadIdx.x;      // t == channel this thread accumulates
  const int lane = t & 63;           // lane == pixel this thread stages
  const int wv   = t >> 6;

  float acc[Kn];
#pragma unroll
  for (int k = 0; k < Kn; k++) acc[k] = 0.0f;

  for (int tid = blockIdx.x; tid < P / 64; tid += gridDim.x) {
    const int p0  = tid << 6;
    const int b   = p0 >> 16;              // HW == 65536
    const int hw0 = p0 & (HW - 1);
    const float* fb = feat + (size_t)b * (Cn * HW) + hw0 + lane;

    __syncthreads();   // previous tile fully consumed

    // stage 64px x 256ch tile; wave wv loads channels [wv*64, wv*64+64)
    float ss = 0.0f;
#pragma unroll 8
    for (int j = 0; j < 64; j++) {
      const int c = (wv << 6) + j;
      const float v = fb[(size_t)c * HW];
      ss += v * v;
      tile[(lane << 8) + (c ^ (lane & 31))] = v;
    }
    part[t] = ss;

    // only wave 0 loads gt (avoid 4x redundant fetch)
    unsigned my_mask = 0;
    if (wv == 0) {
      const float* gb = gt + (size_t)b * (Kn * HW) + hw0 + lane;
#pragma unroll
      for (int k = 0; k < Kn; k++)
        my_mask |= (gb[(size_t)k * HW] == 1.0f) ? (1u << k) : 0u;
    }

    __syncthreads();   // tile + partials visible

    if (wv == 0) {
      const float fss = part[lane] + part[64 + lane] + part[128 + lane] + part[192 + lane];
      const float rn = 1.0f / fmaxf(sqrtf(fss), EPSv);
      pm[lane] = make_float2(rn, __uint_as_float(my_mask));
    }

    __syncthreads();   // pm visible

    // accumulate: thread t owns channel c=t, loops over the 64 pixels
#pragma unroll 4
    for (int p = 0; p < 64; p++) {
      const float2 pr = pm[p];   // broadcast read, conflict-free
      const float rp = __uint_as_float(__builtin_amdgcn_readfirstlane(__float_as_uint(pr.x)));
      const unsigned m = __builtin_amdgcn_readfirstlane(__float_as_uint(pr.y));
      const float fv = tile[(p << 8) + (t ^ (p & 31))] * rp;
#pragma unroll
      for (int k = 0; k < Kn; k++) {
        const float w = (float)((m >> k) & 1u);   // branchless: SALU bit + v_cvt + v_fma
        acc[k] = fmaf(fv, w, acc[k]);
      }
    }
  }

#pragma unroll
  for (int k = 0; k < Kn; k++) atomicAdd(&k0[k * 256 + t], acc[k]);
}

// Phase 2: row-normalize k0 -> k0n, same [K][C] layout
__global__ __launch_bounds__(256) void gc_phase2(const float* __restrict__ k0,
                                                 float* __restrict__ k0n) {
  const int lane = threadIdx.x & 63;
  const int wv   = threadIdx.x >> 6;
  for (int r = wv; r < Kn; r += 4) {
    float s = 0.0f;
#pragma unroll
    for (int j = 0; j < 4; j++) {
      const float v = k0[r * 256 + (j << 6) + lane];
      s += v * v;
    }
#pragma unroll
    for (int off = 32; off > 0; off >>= 1) s += __shfl_down(s, off);
    s = __shfl(s, 0);
    const float rn = 1.0f / fmaxf(sqrtf(s), EPSv);
#pragma unroll
    for (int j = 0; j < 4; j++) {
      const int c = (j << 6) + lane;
      k0n[r * 256 + c] = k0[r * 256 + c] * rn;
    }
  }
}

// Phase 3: per-pixel logits + log-softmax + masked loss accumulation.
// k0n/sums passed as separate __restrict__ pointers so the uniform
// coefficient-row loads can scalarize (s_load) / stay L1-resident.
__global__ __launch_bounds__(256) void gc_phase3(const float* __restrict__ feat,
                                                 const float* __restrict__ gt,
                                                 const float* __restrict__ k0n,
                                                 float* __restrict__ sums) {
  const int t   = threadIdx.x;
  const int pix = (blockIdx.x << 8) + t;
  const int b   = pix >> 16;
  const int hw  = pix & (HW - 1);
  const float* fb = feat + (size_t)b * (Cn * HW) + hw;

  float dot[Kn];
#pragma unroll
  for (int k = 0; k < Kn; k++) dot[k] = 0.0f;
  float ss = 0.0f;

  // c chunked by 16: 16 feat loads in flight, coefficients uniform per chunk
  for (int c0 = 0; c0 < Cn; c0 += 16) {
    float f[16];
#pragma unroll
    for (int j = 0; j < 16; j++) f[j] = fb[(size_t)(c0 + j) * HW];
#pragma unroll
    for (int j = 0; j < 16; j++) ss = fmaf(f[j], f[j], ss);
#pragma unroll
    for (int k = 0; k < Kn; k++) {
      const float* row = k0n + k * 256 + c0;   // contiguous, wave-uniform
      float d = dot[k];
#pragma unroll
      for (int j = 0; j < 16; j++) d = fmaf(f[j], row[j], d);
      dot[k] = d;
    }
  }

  const float sc = 1.0f / (fmaxf(sqrtf(ss), EPSv) * TAUv);
  float mx = -1e30f;
#pragma unroll
  for (int k = 0; k < Kn; k++) { dot[k] *= sc; mx = fmaxf(mx, dot[k]); }
  float se = 0.0f;
#pragma unroll
  for (int k = 0; k < Kn; k++) se += __expf(dot[k] - mx);
  const float lse = __logf(se) + mx;

  const float* gb = gt + (size_t)b * (Kn * HW) + hw;
  float lsum = 0.0f;
  float npos = 0.0f;
#pragma unroll
  for (int k = 0; k < Kn; k++) {
    if (gb[(size_t)k * HW] == 1.0f) { lsum += lse - dot[k]; npos += 1.0f; }
  }

#pragma unroll
  for (int off = 32; off > 0; off >>= 1) {
    lsum += __shfl_down(lsum, off);
    npos += __shfl_down(npos, off);
  }
  if ((t & 63) == 0) {
    atomicAdd(&sums[0], lsum);
    atomicAdd(&sums[1], npos);
  }
}

__global__ void gc_finalize(const float* __restrict__ sums, float* __restrict__ out) {
  if (threadIdx.x == 0 && blockIdx.x == 0)
    out[0] = sums[0] / sums[1];
}

extern "C" void kernel_launch(void* const* d_in, const int* in_sizes, int n_in,
                              void* d_out, int out_size, void* d_ws, size_t ws_size,
                              hipStream_t stream) {
  const float* feat = (const float*)d_in[0];
  const float* gt   = (const float*)d_in[1];
  float* ws  = (float*)d_ws;
  float* out = (float*)d_out;

  float* k0   = ws + K0_OFF;
  float* k0n  = ws + K0N_OFF;
  float* sums = ws + SUMS_OFF;

  gc_init<<<dim3((ZERO_N + 255) / 256), dim3(256), 0, stream>>>(ws);
  gc_phase1<<<dim3(P1_GRID), dim3(256), 0, stream>>>(feat, gt, k0);
  gc_phase2<<<dim3(1), dim3(256), 0, stream>>>(k0, k0n);
  gc_phase3<<<dim3(P / 256), dim3(256), 0, stream>>>(feat, gt, k0n, sums);
  gc_finalize<<<dim3(1), dim3(64), 0, stream>>>(sums, out);
}

// Round 3
// 602.023 us; speedup vs baseline: 1.0844x; 1.0844x over previous
//
#include <hip/hip_runtime.h>
#include <math.h>

namespace {
constexpr int Cn = 256;
constexpr int Kn = 19;
constexpr int HW = 256 * 256;          // 65536
constexpr int P  = 4 * HW;             // 262144 pixels
constexpr float TAUv = 0.07f;
constexpr float EPSv = 1e-12f;

// workspace layout (floats)
constexpr int K0_OFF   = 0;            // [19][256] prototype accumulators
constexpr int K0N_OFF  = 4864;         // [19][256] normalized prototypes
constexpr int SUMS_OFF = 9728;         // {loss_sum, num_pos}
constexpr int ZERO_N   = 9730;
constexpr int P1_GRID  = 1024;
constexpr int P3_GRID  = P / 256;      // 1024
}

__global__ __launch_bounds__(256) void gc_init(float* __restrict__ ws) {
  int i = blockIdx.x * 256 + threadIdx.x;
  if (i < ZERO_N) ws[i] = 0.0f;
}

// Phase 1: k0[k][c] = sum over pixels of pos[k,p] * fnorm[c,p]
// 32px x 256c tile (32 KB -> 4 blocks/CU). Thread t accumulates channel c=t.
// Per-pixel weights w[p][k] = (pos ? rnorm : 0) precomputed once per tile,
// so the inner loop is pure FMA (no cvt, no rnorm multiply).
__global__ __launch_bounds__(256, 4) void gc_phase1(const float* __restrict__ feat,
                                                    const float* __restrict__ gt,
                                                    float* __restrict__ k0) {
  __shared__ float tile[32 * 256];   // [p][c ^ p], 32 KB
  __shared__ float part[256];        // sumsq partials
  __shared__ float wls[32][20];      // [p][k] weights, padded to 20 (16B-aligned rows)

  const int t = threadIdx.x;
  const int p = t & 31;              // pixel this thread stages
  const int g = t >> 5;              // channel group (8 groups of 32)

  float acc[Kn];
#pragma unroll
  for (int k = 0; k < Kn; k++) acc[k] = 0.0f;

  for (int tid = blockIdx.x; tid < P / 32; tid += gridDim.x) {
    const int p0  = tid << 5;
    const int b   = p0 >> 16;              // HW == 65536
    const int hw0 = p0 & (HW - 1);
    const float* fb = feat + (size_t)b * (Cn * HW) + hw0;

    __syncthreads();   // previous tile fully consumed

    // stage: thread t loads pixel p, channels g*32+j (32 loads in flight)
    float v[32];
#pragma unroll
    for (int j = 0; j < 32; j++) v[j] = fb[(size_t)((g << 5) + j) * HW + p];
    float ss = 0.0f;
#pragma unroll
    for (int j = 0; j < 32; j++) {
      const int c = (g << 5) + j;
      ss += v[j] * v[j];
      tile[(p << 8) + (c ^ p)] = v[j];
    }
    part[t] = ss;

    unsigned msk = 0;
    if (t < 32) {   // t == p here; gt fetched once per pixel
      const float* gb = gt + (size_t)b * (Kn * HW) + hw0 + p;
#pragma unroll
      for (int k = 0; k < Kn; k++)
        msk |= (gb[(size_t)k * HW] == 1.0f) ? (1u << k) : 0u;
    }

    __syncthreads();   // tile + partials visible

    if (t < 32) {
      float fss = 0.0f;
#pragma unroll
      for (int q = 0; q < 8; q++) fss += part[(q << 5) + p];
      const float rn = 1.0f / fmaxf(sqrtf(fss), EPSv);
#pragma unroll
      for (int k = 0; k < Kn; k++) wls[p][k] = ((msk >> k) & 1u) ? rn : 0.0f;
      wls[p][19] = 0.0f;
    }

    __syncthreads();   // wls visible

    // accumulate: thread t owns channel c=t, loops over the 32 pixels
#pragma unroll 4
    for (int pp = 0; pp < 32; pp++) {
      const float4 w0 = *(const float4*)&wls[pp][0];
      const float4 w1 = *(const float4*)&wls[pp][4];
      const float4 w2 = *(const float4*)&wls[pp][8];
      const float4 w3 = *(const float4*)&wls[pp][12];
      const float4 w4 = *(const float4*)&wls[pp][16];   // .w is pad
      const float fv = tile[(pp << 8) + (t ^ pp)];
      acc[0]  = fmaf(fv, w0.x, acc[0]);  acc[1]  = fmaf(fv, w0.y, acc[1]);
      acc[2]  = fmaf(fv, w0.z, acc[2]);  acc[3]  = fmaf(fv, w0.w, acc[3]);
      acc[4]  = fmaf(fv, w1.x, acc[4]);  acc[5]  = fmaf(fv, w1.y, acc[5]);
      acc[6]  = fmaf(fv, w1.z, acc[6]);  acc[7]  = fmaf(fv, w1.w, acc[7]);
      acc[8]  = fmaf(fv, w2.x, acc[8]);  acc[9]  = fmaf(fv, w2.y, acc[9]);
      acc[10] = fmaf(fv, w2.z, acc[10]); acc[11] = fmaf(fv, w2.w, acc[11]);
      acc[12] = fmaf(fv, w3.x, acc[12]); acc[13] = fmaf(fv, w3.y, acc[13]);
      acc[14] = fmaf(fv, w3.z, acc[14]); acc[15] = fmaf(fv, w3.w, acc[15]);
      acc[16] = fmaf(fv, w4.x, acc[16]); acc[17] = fmaf(fv, w4.y, acc[17]);
      acc[18] = fmaf(fv, w4.z, acc[18]);
    }
  }

#pragma unroll
  for (int k = 0; k < Kn; k++) atomicAdd(&k0[k * 256 + t], acc[k]);
}

// Phase 2: row-normalize k0 -> k0n
__global__ __launch_bounds__(256) void gc_phase2(const float* __restrict__ k0,
                                                 float* __restrict__ k0n) {
  const int lane = threadIdx.x & 63;
  const int wv   = threadIdx.x >> 6;
  for (int r = wv; r < Kn; r += 4) {
    float s = 0.0f;
#pragma unroll
    for (int j = 0; j < 4; j++) {
      const float v = k0[r * 256 + (j << 6) + lane];
      s += v * v;
    }
#pragma unroll
    for (int off = 32; off > 0; off >>= 1) s += __shfl_down(s, off);
    s = __shfl(s, 0);
    const float rn = 1.0f / fmaxf(sqrtf(s), EPSv);
#pragma unroll
    for (int j = 0; j < 4; j++) {
      const int c = (j << 6) + lane;
      k0n[r * 256 + c] = k0[r * 256 + c] * rn;
    }
  }
}

// Phase 3: logits + log-softmax + masked loss.
// feat staged through LDS in 16-channel chunks (prefetch next chunk before
// consuming current); k0n staged once into LDS, read as uniform float4
// broadcasts. Thread t owns pixel blockIdx*256+t.
__global__ __launch_bounds__(256, 4) void gc_phase3(const float* __restrict__ feat,
                                                    const float* __restrict__ gt,
                                                    const float* __restrict__ k0n,
                                                    float* __restrict__ sums) {
  __shared__ float wco[Kn * 256];    // 19 KB coefficients
  __shared__ float tile[16 * 256];   // 16 KB, [c][px] conflict-free

  const int t = threadIdx.x;
#pragma unroll
  for (int i = 0; i < Kn; i++) wco[i * 256 + t] = k0n[i * 256 + t];

  const int pix0 = blockIdx.x << 8;
  const int b    = pix0 >> 16;
  const int hw   = (pix0 & (HW - 1)) + t;
  const float* fb = feat + (size_t)b * (Cn * HW) + hw;

  float dot[Kn];
#pragma unroll
  for (int k = 0; k < Kn; k++) dot[k] = 0.0f;
  float ss = 0.0f;

  float v[16];
#pragma unroll
  for (int j = 0; j < 16; j++) v[j] = fb[(size_t)j * HW];   // prefetch chunk 0

  for (int c0 = 0; c0 < Cn; c0 += 16) {
    __syncthreads();   // previous chunk consumed (covers wco on first iter)
#pragma unroll
    for (int j = 0; j < 16; j++) tile[j * 256 + t] = v[j];
    __syncthreads();   // tile ready

    if (c0 + 16 < Cn) {   // prefetch next chunk before consuming this one
#pragma unroll
      for (int j = 0; j < 16; j++) v[j] = fb[(size_t)(c0 + 16 + j) * HW];
    }

#pragma unroll
    for (int j4 = 0; j4 < 16; j4 += 4) {
      const float f0 = tile[(j4 + 0) * 256 + t];
      const float f1 = tile[(j4 + 1) * 256 + t];
      const float f2 = tile[(j4 + 2) * 256 + t];
      const float f3 = tile[(j4 + 3) * 256 + t];
      ss = fmaf(f0, f0, ss); ss = fmaf(f1, f1, ss);
      ss = fmaf(f2, f2, ss); ss = fmaf(f3, f3, ss);
#pragma unroll
      for (int k = 0; k < Kn; k++) {
        const float4 w = *(const float4*)&wco[k * 256 + c0 + j4];  // broadcast
        dot[k] = fmaf(f3, w.w, fmaf(f2, w.z, fmaf(f1, w.y, fmaf(f0, w.x, dot[k]))));
      }
    }
  }

  const float sc = 1.0f / (fmaxf(sqrtf(ss), EPSv) * TAUv);
  float mx = -1e30f;
#pragma unroll
  for (int k = 0; k < Kn; k++) { dot[k] *= sc; mx = fmaxf(mx, dot[k]); }
  float se = 0.0f;
#pragma unroll
  for (int k = 0; k < Kn; k++) se += __expf(dot[k] - mx);
  const float lse = __logf(se) + mx;

  const float* gb = gt + (size_t)b * (Kn * HW) + hw;
  float lsum = 0.0f, npos = 0.0f;
#pragma unroll
  for (int k = 0; k < Kn; k++) {
    if (gb[(size_t)k * HW] == 1.0f) { lsum += lse - dot[k]; npos += 1.0f; }
  }

#pragma unroll
  for (int off = 32; off > 0; off >>= 1) {
    lsum += __shfl_down(lsum, off);
    npos += __shfl_down(npos, off);
  }
  if ((t & 63) == 0) {
    atomicAdd(&sums[0], lsum);
    atomicAdd(&sums[1], npos);
  }
}

__global__ void gc_finalize(const float* __restrict__ sums, float* __restrict__ out) {
  if (threadIdx.x == 0 && blockIdx.x == 0)
    out[0] = sums[0] / sums[1];
}

extern "C" void kernel_launch(void* const* d_in, const int* in_sizes, int n_in,
                              void* d_out, int out_size, void* d_ws, size_t ws_size,
                              hipStream_t stream) {
  const float* feat = (const float*)d_in[0];
  const float* gt   = (const float*)d_in[1];
  float* ws  = (float*)d_ws;
  float* out = (float*)d_out;

  float* k0   = ws + K0_OFF;
  float* k0n  = ws + K0N_OFF;
  float* sums = ws + SUMS_OFF;

  gc_init<<<dim3((ZERO_N + 255) / 256), dim3(256), 0, stream>>>(ws);
  gc_phase1<<<dim3(P1_GRID), dim3(256), 0, stream>>>(feat, gt, k0);
  gc_phase2<<<dim3(1), dim3(256), 0, stream>>>(k0, k0n);
  gc_phase3<<<dim3(P3_GRID), dim3(256), 0, stream>>>(feat, gt, k0n, sums);
  gc_finalize<<<dim3(1), dim3(64), 0, stream>>>(sums, out);
}